// Round 13
// baseline (190.487 us; speedup 1.0000x reference)
//
#include <hip/hip_runtime.h>
#include <hip/hip_bf16.h>
#include <stdint.h>

#define IN_SZ   256
#define OUT_SZ  256
#define RANK    60
#define NSEL    256
#define BATCH   1024
#define WELEMS  (IN_SZ * OUT_SZ)   // 65536 elems per channel

typedef __attribute__((ext_vector_type(8))) short          short8;
typedef __attribute__((ext_vector_type(4))) float          f32x4;

static __device__ __forceinline__ unsigned short f32_to_bf16(float f) {
    union { float f; uint32_t u; } c; c.f = f;
    uint32_t u = c.u;
    u += 0x7fffu + ((u >> 16) & 1u);   // RNE
    return (unsigned short)(u >> 16);
}

// pair-packed RNE convert — compiler emits v_cvt_pk_bf16_f32 (same rounding)
static __device__ __forceinline__ short8 cvt8(f32x4 lo, f32x4 hi) {
    union { short8 s; __hip_bfloat162 h[4]; } u;
    u.h[0] = __float22bfloat162_rn(make_float2(lo[0], lo[1]));
    u.h[1] = __float22bfloat162_rn(make_float2(lo[2], lo[3]));
    u.h[2] = __float22bfloat162_rn(make_float2(hi[0], hi[1]));
    u.h[3] = __float22bfloat162_rn(make_float2(hi[2], hi[3]));
    return u.s;
}

// -----------------------------------------------------------------------------
// Kernel 1: W_sel = U[idx] @ V -> bf16 in B-FRAGMENT-MAJOR layout:
//   wt[n][koct*2048 + o*8 + il]   (koct = i>>3, il = i&7)
// (unchanged — verified correct, ~24 µs)
// -----------------------------------------------------------------------------
__global__ __launch_bounds__(256) void synth_w(
    const float* __restrict__ U, const float* __restrict__ V,
    const int* __restrict__ idx, unsigned short* __restrict__ wt)
{
    __shared__ unsigned short Cs[16][2064];

    int bid = blockIdx.x;                  // 512 blocks
    int L   = (bid & 7) * 64 + (bid >> 3); // XCD swizzle: same-ic -> same XCD
    int ic  = L >> 4;
    int g16 = L & 15;

    int tid = threadIdx.x, lane = tid & 63, wv = tid >> 6;

    int arow = lane & 15;
    int c    = idx[g16 * 16 + arow];
    short8 afr[2];
    #pragma unroll
    for (int ks = 0; ks < 2; ++ks) {
        short8 h;
        #pragma unroll
        for (int j = 0; j < 8; ++j) {
            int r = ks * 32 + (lane >> 4) * 8 + j;
            float u = (r < RANK) ? U[c * RANK + r] : 0.f;
            h[j] = (short)f32_to_bf16(u);
        }
        afr[ks] = h;
    }

    const float* Vb = V + (size_t)ic * 2048;
    #pragma unroll 2
    for (int mt = 0; mt < 32; ++mt) {
        int mloc = (wv * 32 + mt) * 16 + (lane & 15);
        f32x4 acc = {};
        #pragma unroll
        for (int ks = 0; ks < 2; ++ks) {
            short8 b;
            #pragma unroll
            for (int j = 0; j < 8; ++j) {
                int r = ks * 32 + (lane >> 4) * 8 + j;
                float v = (r < RANK) ? Vb[(size_t)r * WELEMS + mloc] : 0.f;
                b[j] = (short)f32_to_bf16(v);
            }
            acc = __builtin_amdgcn_mfma_f32_16x16x32_bf16(afr[ks], b, acc, 0, 0, 0);
        }
        #pragma unroll
        for (int j = 0; j < 4; ++j) {
            int nl = (lane >> 4) * 4 + j;
            Cs[nl][wv * 512 + mt * 16 + (lane & 15)] = f32_to_bf16(acc[j]);
        }
    }
    __syncthreads();

    #pragma unroll
    for (int t0 = 0; t0 < 16; ++t0) {
        int t  = t0 * 256 + tid;
        int nl = t >> 8;
        int o  = t & 255;
        short8 h;
        #pragma unroll
        for (int il = 0; il < 8; ++il) h[il] = (short)Cs[nl][il * 256 + o];
        int n = g16 * 16 + nl;
        size_t base = (size_t)n * WELEMS + (size_t)ic * 2048 + (size_t)o * 8;
        *reinterpret_cast<short8*>(wt + base) = h;
    }
}

// -----------------------------------------------------------------------------
// Kernel 2: W-RESIDENT-IN-LDS GEMM. One block per n (256 blocks, 512 threads).
// W[n] (128 KB bf16, fragment-major) DMA'd to LDS once + bias (1 KB); ONE
// barrier; then 8 free-running waves, each owning 128 rows, sweep 16-row
// chunks: A per-lane from global x (coalesced 128B segments, x read once),
// B from LDS (4x256B groups/instr -> uniform banks), acc init = bias.
// A double-buffered in named regs (prefetch issued before compute).
// No B memory-hierarchy traffic, no phase-lock, nothing between a wave and
// the HBM stream.
// -----------------------------------------------------------------------------
__global__ __launch_bounds__(512, 2) void gemm_k(
    const float* __restrict__ x, const int* __restrict__ idx,
    const unsigned short* __restrict__ wt, const float* __restrict__ bias,
    float* __restrict__ out)
{
    __shared__ __align__(16) unsigned short Wl[WELEMS];   // 128 KB
    __shared__ __align__(16) float          Bl[256];      // 1 KB bias

    int n    = blockIdx.x;                 // 0..255, one n per block
    int tid  = threadIdx.x;
    int lane = tid & 63;
    int wv   = tid >> 6;                   // 0..7
    int r16  = lane & 15;
    int q    = lane >> 4;

    const unsigned short* wn = wt + (size_t)n * WELEMS;

    // ---- stage W[n]: 128 x 1KB linear DMA segments (flat copy) ----
    #pragma unroll
    for (int j = 0; j < 16; ++j) {
        int g = wv * 16 + j;               // 0..127
        __builtin_amdgcn_global_load_lds(
            (const __attribute__((address_space(1))) void*)(wn + g * 512 + lane * 8),
            (__attribute__((address_space(3))) void*)(&Wl[g * 512]),
            16, 0, 0);
    }
    // ---- stage bias[c] ----
    int c = idx[n];
    if (tid < 64) {
        f32x4 b = *reinterpret_cast<const f32x4*>(bias + (size_t)c * OUT_SZ + tid * 4);
        *reinterpret_cast<f32x4*>(&Bl[tid * 4]) = b;
    }
    __syncthreads();   // the only barrier (drains DMA + ds_write)

    const float* xw = x + (size_t)n * (BATCH * IN_SZ)
                        + (size_t)(wv * 128 + r16) * IN_SZ + q * 8;
    float*       ow = out + (size_t)n * (BATCH * OUT_SZ)
                        + (size_t)(wv * 128 + r16) * OUT_SZ + q * 4;
    const char*  wl = reinterpret_cast<const char*>(Wl);
    int lq = q * 4096 + r16 * 16;          // lane's byte base into Wl

    f32x4 A0[8][2], A1[8][2];

    auto loadA = [&](f32x4 (&Ab)[8][2], int t) {
        const float* xp = xw + (size_t)t * 16 * IN_SZ;
        #pragma unroll
        for (int ks = 0; ks < 8; ++ks) {
            Ab[ks][0] = *reinterpret_cast<const f32x4*>(xp + ks * 32);
            Ab[ks][1] = *reinterpret_cast<const f32x4*>(xp + ks * 32 + 4);
        }
    };

    loadA(A0, 0);

    #pragma unroll
    for (int t = 0; t < 8; ++t) {
        f32x4 (&Ac)[8][2] = (t & 1) ? A1 : A0;   // static after unroll
        f32x4 (&An)[8][2] = (t & 1) ? A0 : A1;
        if (t < 7) loadA(An, t + 1);             // 16 loads in flight over compute

        f32x4 acc[16];
        #pragma unroll
        for (int nf = 0; nf < 16; ++nf)          // acc init = bias (broadcast read)
            acc[nf] = *reinterpret_cast<const f32x4*>(&Bl[nf * 16 + q * 4]);

        #pragma unroll
        for (int ks = 0; ks < 8; ++ks) {
            short8 af = cvt8(Ac[ks][0], Ac[ks][1]);
            #pragma unroll
            for (int nf = 0; nf < 16; ++nf) {
                short8 bf = *reinterpret_cast<const short8*>(
                    wl + lq + ks * 16384 + nf * 256);
                acc[nf] = __builtin_amdgcn_mfma_f32_16x16x32_bf16(
                    bf, af, acc[nf], 0, 0, 0);   // swapped: out^T frag
            }
        }

        float* op = ow + (size_t)t * 16 * OUT_SZ;
        #pragma unroll
        for (int nf = 0; nf < 16; ++nf)
            *reinterpret_cast<f32x4*>(op + nf * 16) = acc[nf];
    }
}

extern "C" void kernel_launch(void* const* d_in, const int* in_sizes, int n_in,
                              void* d_out, int out_size, void* d_ws, size_t ws_size,
                              hipStream_t stream) {
    const float* x    = (const float*)d_in[0];
    const int*   idx  = (const int*)  d_in[1];
    const float* U    = (const float*)d_in[2];
    const float* V    = (const float*)d_in[3];
    const float* bias = (const float*)d_in[4];
    float* out = (float*)d_out;
    unsigned short* wt = (unsigned short*)d_ws;   // 32 MB scratch
    (void)in_sizes; (void)n_in; (void)out_size; (void)ws_size;

    synth_w<<<dim3(512), dim3(256), 0, stream>>>(U, V, idx, wt);
    gemm_k <<<dim3(256), dim3(512), 0, stream>>>(x, idx, wt, bias, out);
}

// Round 14
// 189.115 us; speedup vs baseline: 1.0073x; 1.0073x over previous
//
#include <hip/hip_runtime.h>
#include <hip/hip_bf16.h>
#include <stdint.h>

#define IN_SZ   256
#define OUT_SZ  256
#define RANK    60
#define NSEL    256
#define BATCH   1024
#define WELEMS  (IN_SZ * OUT_SZ)   // 65536 elems per channel

typedef __attribute__((ext_vector_type(8))) short          short8;
typedef __attribute__((ext_vector_type(4))) float          f32x4;

static __device__ __forceinline__ unsigned short f32_to_bf16(float f) {
    union { float f; uint32_t u; } c; c.f = f;
    uint32_t u = c.u;
    u += 0x7fffu + ((u >> 16) & 1u);   // RNE
    return (unsigned short)(u >> 16);
}

// pair-packed RNE convert — compiler emits v_cvt_pk_bf16_f32 (same rounding)
static __device__ __forceinline__ short8 cvt8(f32x4 lo, f32x4 hi) {
    union { short8 s; __hip_bfloat162 h[4]; } u;
    u.h[0] = __float22bfloat162_rn(make_float2(lo[0], lo[1]));
    u.h[1] = __float22bfloat162_rn(make_float2(lo[2], lo[3]));
    u.h[2] = __float22bfloat162_rn(make_float2(hi[0], hi[1]));
    u.h[3] = __float22bfloat162_rn(make_float2(hi[2], hi[3]));
    return u.s;
}

// -----------------------------------------------------------------------------
// Kernel 1: W_sel = U[idx] @ V -> bf16 in B-FRAGMENT-MAJOR layout:
//   wt[n][koct*2048 + o*8 + il]   (koct = i>>3, il = i&7)
// (unchanged — verified correct, ~24 µs)
// -----------------------------------------------------------------------------
__global__ __launch_bounds__(256) void synth_w(
    const float* __restrict__ U, const float* __restrict__ V,
    const int* __restrict__ idx, unsigned short* __restrict__ wt)
{
    __shared__ unsigned short Cs[16][2064];

    int bid = blockIdx.x;                  // 512 blocks
    int L   = (bid & 7) * 64 + (bid >> 3); // XCD swizzle: same-ic -> same XCD
    int ic  = L >> 4;
    int g16 = L & 15;

    int tid = threadIdx.x, lane = tid & 63, wv = tid >> 6;

    int arow = lane & 15;
    int c    = idx[g16 * 16 + arow];
    short8 afr[2];
    #pragma unroll
    for (int ks = 0; ks < 2; ++ks) {
        short8 h;
        #pragma unroll
        for (int j = 0; j < 8; ++j) {
            int r = ks * 32 + (lane >> 4) * 8 + j;
            float u = (r < RANK) ? U[c * RANK + r] : 0.f;
            h[j] = (short)f32_to_bf16(u);
        }
        afr[ks] = h;
    }

    const float* Vb = V + (size_t)ic * 2048;
    #pragma unroll 2
    for (int mt = 0; mt < 32; ++mt) {
        int mloc = (wv * 32 + mt) * 16 + (lane & 15);
        f32x4 acc = {};
        #pragma unroll
        for (int ks = 0; ks < 2; ++ks) {
            short8 b;
            #pragma unroll
            for (int j = 0; j < 8; ++j) {
                int r = ks * 32 + (lane >> 4) * 8 + j;
                float v = (r < RANK) ? Vb[(size_t)r * WELEMS + mloc] : 0.f;
                b[j] = (short)f32_to_bf16(v);
            }
            acc = __builtin_amdgcn_mfma_f32_16x16x32_bf16(afr[ks], b, acc, 0, 0, 0);
        }
        #pragma unroll
        for (int j = 0; j < 4; ++j) {
            int nl = (lane >> 4) * 4 + j;
            Cs[nl][wv * 512 + mt * 16 + (lane & 15)] = f32_to_bf16(acc[j]);
        }
    }
    __syncthreads();

    #pragma unroll
    for (int t0 = 0; t0 < 16; ++t0) {
        int t  = t0 * 256 + tid;
        int nl = t >> 8;
        int o  = t & 255;
        short8 h;
        #pragma unroll
        for (int il = 0; il < 8; ++il) h[il] = (short)Cs[nl][il * 256 + o];
        int n = g16 * 16 + nl;
        size_t base = (size_t)n * WELEMS + (size_t)ic * 2048 + (size_t)o * 8;
        *reinterpret_cast<short8*>(wt + base) = h;
    }
}

// -----------------------------------------------------------------------------
// Kernel 2: W-RESIDENT-IN-LDS GEMM. One block per n (256 blocks, 512 threads).
// W[n] (128 KB bf16, fragment-major) DMA'd to LDS once + bias (1 KB); ONE
// barrier; then 8 free-running waves, each owning 128 rows, sweep 16-row
// chunks: A per-lane from global x (coalesced 128B segments, x read once),
// B from LDS (4x256B groups/instr -> conflict-free, measured 0), acc init =
// bias. A double-buffered in named regs.
// R14 fix: __launch_bounds__(512) — no waves/EU constraint, VGPR cap 512;
// demand ~210 fits, no spills (R13 had VGPR=128 + 47MB scratch traffic).
// -----------------------------------------------------------------------------
__global__ __launch_bounds__(512) void gemm_k(
    const float* __restrict__ x, const int* __restrict__ idx,
    const unsigned short* __restrict__ wt, const float* __restrict__ bias,
    float* __restrict__ out)
{
    __shared__ __align__(16) unsigned short Wl[WELEMS];   // 128 KB
    __shared__ __align__(16) float          Bl[256];      // 1 KB bias

    int n    = blockIdx.x;                 // 0..255, one n per block
    int tid  = threadIdx.x;
    int lane = tid & 63;
    int wv   = tid >> 6;                   // 0..7
    int r16  = lane & 15;
    int q    = lane >> 4;

    const unsigned short* wn = wt + (size_t)n * WELEMS;

    // ---- stage W[n]: 128 x 1KB linear DMA segments (flat copy) ----
    #pragma unroll
    for (int j = 0; j < 16; ++j) {
        int g = wv * 16 + j;               // 0..127
        __builtin_amdgcn_global_load_lds(
            (const __attribute__((address_space(1))) void*)(wn + g * 512 + lane * 8),
            (__attribute__((address_space(3))) void*)(&Wl[g * 512]),
            16, 0, 0);
    }
    // ---- stage bias[c] ----
    int c = idx[n];
    if (tid < 64) {
        f32x4 b = *reinterpret_cast<const f32x4*>(bias + (size_t)c * OUT_SZ + tid * 4);
        *reinterpret_cast<f32x4*>(&Bl[tid * 4]) = b;
    }
    __syncthreads();   // the only barrier (drains DMA + ds_write)

    const float* xw = x + (size_t)n * (BATCH * IN_SZ)
                        + (size_t)(wv * 128 + r16) * IN_SZ + q * 8;
    float*       ow = out + (size_t)n * (BATCH * OUT_SZ)
                        + (size_t)(wv * 128 + r16) * OUT_SZ + q * 4;
    const char*  wl = reinterpret_cast<const char*>(Wl);
    int lq = q * 4096 + r16 * 16;          // lane's byte base into Wl

    f32x4 A0[8][2], A1[8][2];

    auto loadA = [&](f32x4 (&Ab)[8][2], int t) {
        const float* xp = xw + (size_t)t * 16 * IN_SZ;
        #pragma unroll
        for (int ks = 0; ks < 8; ++ks) {
            Ab[ks][0] = *reinterpret_cast<const f32x4*>(xp + ks * 32);
            Ab[ks][1] = *reinterpret_cast<const f32x4*>(xp + ks * 32 + 4);
        }
    };

    loadA(A0, 0);

    #pragma unroll
    for (int t = 0; t < 8; ++t) {
        f32x4 (&Ac)[8][2] = (t & 1) ? A1 : A0;   // static after unroll
        f32x4 (&An)[8][2] = (t & 1) ? A0 : A1;
        if (t < 7) loadA(An, t + 1);             // 16 loads in flight over compute

        f32x4 acc[16];
        #pragma unroll
        for (int nf = 0; nf < 16; ++nf)          // acc init = bias (broadcast read)
            acc[nf] = *reinterpret_cast<const f32x4*>(&Bl[nf * 16 + q * 4]);

        #pragma unroll
        for (int ks = 0; ks < 8; ++ks) {
            short8 af = cvt8(Ac[ks][0], Ac[ks][1]);
            #pragma unroll
            for (int nf = 0; nf < 16; ++nf) {
                short8 bf = *reinterpret_cast<const short8*>(
                    wl + lq + ks * 16384 + nf * 256);
                acc[nf] = __builtin_amdgcn_mfma_f32_16x16x32_bf16(
                    bf, af, acc[nf], 0, 0, 0);   // swapped: out^T frag
            }
        }

        float* op = ow + (size_t)t * 16 * OUT_SZ;
        #pragma unroll
        for (int nf = 0; nf < 16; ++nf)
            *reinterpret_cast<f32x4*>(op + nf * 16) = acc[nf];
    }
}

extern "C" void kernel_launch(void* const* d_in, const int* in_sizes, int n_in,
                              void* d_out, int out_size, void* d_ws, size_t ws_size,
                              hipStream_t stream) {
    const float* x    = (const float*)d_in[0];
    const int*   idx  = (const int*)  d_in[1];
    const float* U    = (const float*)d_in[2];
    const float* V    = (const float*)d_in[3];
    const float* bias = (const float*)d_in[4];
    float* out = (float*)d_out;
    unsigned short* wt = (unsigned short*)d_ws;   // 32 MB scratch
    (void)in_sizes; (void)n_in; (void)out_size; (void)ws_size;

    synth_w<<<dim3(512), dim3(256), 0, stream>>>(U, V, idx, wt);
    gemm_k <<<dim3(256), dim3(512), 0, stream>>>(x, idx, wt, bias, out);
}

// Round 15
// 163.788 us; speedup vs baseline: 1.1630x; 1.1546x over previous
//
#include <hip/hip_runtime.h>
#include <hip/hip_bf16.h>
#include <stdint.h>

#define IN_SZ   256
#define OUT_SZ  256
#define RANK    60
#define NSEL    256
#define BATCH   1024
#define WELEMS  (IN_SZ * OUT_SZ)   // 65536 elems per channel

typedef __attribute__((ext_vector_type(8))) short          short8;
typedef __attribute__((ext_vector_type(4))) float          f32x4;

static __device__ __forceinline__ unsigned short f32_to_bf16(float f) {
    union { float f; uint32_t u; } c; c.f = f;
    uint32_t u = c.u;
    u += 0x7fffu + ((u >> 16) & 1u);   // RNE
    return (unsigned short)(u >> 16);
}

// pair-packed RNE convert — compiler emits v_cvt_pk_bf16_f32 (same rounding)
static __device__ __forceinline__ short8 cvt8(f32x4 lo, f32x4 hi) {
    union { short8 s; __hip_bfloat162 h[4]; } u;
    u.h[0] = __float22bfloat162_rn(make_float2(lo[0], lo[1]));
    u.h[1] = __float22bfloat162_rn(make_float2(lo[2], lo[3]));
    u.h[2] = __float22bfloat162_rn(make_float2(hi[0], hi[1]));
    u.h[3] = __float22bfloat162_rn(make_float2(hi[2], hi[3]));
    return u.s;
}

// -----------------------------------------------------------------------------
// Kernel 1: W_sel = U[idx] @ V -> bf16 in B-FRAGMENT-MAJOR layout:
//   wt[n][koct*2048 + o*8 + il]   (koct = i>>3, il = i&7)
// (unchanged — verified correct, ~24 µs)
// -----------------------------------------------------------------------------
__global__ __launch_bounds__(256) void synth_w(
    const float* __restrict__ U, const float* __restrict__ V,
    const int* __restrict__ idx, unsigned short* __restrict__ wt)
{
    __shared__ unsigned short Cs[16][2064];

    int bid = blockIdx.x;                  // 512 blocks
    int L   = (bid & 7) * 64 + (bid >> 3); // XCD swizzle: same-ic -> same XCD
    int ic  = L >> 4;
    int g16 = L & 15;

    int tid = threadIdx.x, lane = tid & 63, wv = tid >> 6;

    int arow = lane & 15;
    int c    = idx[g16 * 16 + arow];
    short8 afr[2];
    #pragma unroll
    for (int ks = 0; ks < 2; ++ks) {
        short8 h;
        #pragma unroll
        for (int j = 0; j < 8; ++j) {
            int r = ks * 32 + (lane >> 4) * 8 + j;
            float u = (r < RANK) ? U[c * RANK + r] : 0.f;
            h[j] = (short)f32_to_bf16(u);
        }
        afr[ks] = h;
    }

    const float* Vb = V + (size_t)ic * 2048;
    #pragma unroll 2
    for (int mt = 0; mt < 32; ++mt) {
        int mloc = (wv * 32 + mt) * 16 + (lane & 15);
        f32x4 acc = {};
        #pragma unroll
        for (int ks = 0; ks < 2; ++ks) {
            short8 b;
            #pragma unroll
            for (int j = 0; j < 8; ++j) {
                int r = ks * 32 + (lane >> 4) * 8 + j;
                float v = (r < RANK) ? Vb[(size_t)r * WELEMS + mloc] : 0.f;
                b[j] = (short)f32_to_bf16(v);
            }
            acc = __builtin_amdgcn_mfma_f32_16x16x32_bf16(afr[ks], b, acc, 0, 0, 0);
        }
        #pragma unroll
        for (int j = 0; j < 4; ++j) {
            int nl = (lane >> 4) * 4 + j;
            Cs[nl][wv * 512 + mt * 16 + (lane & 15)] = f32_to_bf16(acc[j]);
        }
    }
    __syncthreads();

    #pragma unroll
    for (int t0 = 0; t0 < 16; ++t0) {
        int t  = t0 * 256 + tid;
        int nl = t >> 8;
        int o  = t & 255;
        short8 h;
        #pragma unroll
        for (int il = 0; il < 8; ++il) h[il] = (short)Cs[nl][il * 256 + o];
        int n = g16 * 16 + nl;
        size_t base = (size_t)n * WELEMS + (size_t)ic * 2048 + (size_t)o * 8;
        *reinterpret_cast<short8*>(wt + base) = h;
    }
}

// -----------------------------------------------------------------------------
// Kernel 2: W-RESIDENT-IN-LDS GEMM. One block per n (256 blocks, 512 threads).
// W[n] (128 KB bf16) DMA'd to LDS once + bias (1 KB); ONE barrier; 8
// free-running waves sweep 16-row chunks. A per-lane from global (coalesced),
// B from LDS (conflict-free, measured 0), acc init = bias.
// R15 fix: A prefetch shrunk to two HALF-TILE buffers (4 ks each, 64 VGPR
// total) in a depth-1 pipeline over 16 half-steps -> arch demand ~100 regs,
// fits the 128-reg step alongside 64 acc AGPRs; no scratch spill (R13/R14
// spilled 48 MB: demand 210+64 > 256 unified cap for 512-thr blocks).
// -----------------------------------------------------------------------------
__global__ __launch_bounds__(512, 2) void gemm_k(
    const float* __restrict__ x, const int* __restrict__ idx,
    const unsigned short* __restrict__ wt, const float* __restrict__ bias,
    float* __restrict__ out)
{
    __shared__ __align__(16) unsigned short Wl[WELEMS];   // 128 KB
    __shared__ __align__(16) float          Bl[256];      // 1 KB bias

    int n    = blockIdx.x;                 // 0..255, one n per block
    int tid  = threadIdx.x;
    int lane = tid & 63;
    int wv   = tid >> 6;                   // 0..7
    int r16  = lane & 15;
    int q    = lane >> 4;

    const unsigned short* wn = wt + (size_t)n * WELEMS;

    // ---- stage W[n]: 128 x 1KB linear DMA segments (flat copy) ----
    #pragma unroll
    for (int j = 0; j < 16; ++j) {
        int g = wv * 16 + j;               // 0..127
        __builtin_amdgcn_global_load_lds(
            (const __attribute__((address_space(1))) void*)(wn + g * 512 + lane * 8),
            (__attribute__((address_space(3))) void*)(&Wl[g * 512]),
            16, 0, 0);
    }
    // ---- stage bias[c] ----
    int c = idx[n];
    if (tid < 64) {
        f32x4 b = *reinterpret_cast<const f32x4*>(bias + (size_t)c * OUT_SZ + tid * 4);
        *reinterpret_cast<f32x4*>(&Bl[tid * 4]) = b;
    }
    __syncthreads();   // the only barrier (drains DMA + ds_write)

    const float* xw = x + (size_t)n * (BATCH * IN_SZ)
                        + (size_t)(wv * 128 + r16) * IN_SZ + q * 8;
    float*       ow = out + (size_t)n * (BATCH * OUT_SZ)
                        + (size_t)(wv * 128 + r16) * OUT_SZ + q * 4;
    const char*  wl = reinterpret_cast<const char*>(Wl);
    int lq = q * 4096 + r16 * 16;          // lane's byte base into Wl

    // Two HALF-TILE prefetch buffers: 4 ks x 8 floats = 32 VGPR each.
    f32x4 P0[4][2], P1[4][2];

    // half-step s = 2*t + h  (t = 16-row chunk, h = ks-half)
    auto loadHalf = [&](f32x4 (&P)[4][2], int s) {
        const float* xp = xw + (size_t)(s >> 1) * 16 * IN_SZ + (s & 1) * 128;
        #pragma unroll
        for (int k = 0; k < 4; ++k) {
            P[k][0] = *reinterpret_cast<const f32x4*>(xp + k * 32);
            P[k][1] = *(reinterpret_cast<const f32x4*>(xp + k * 32) + 1);
        }
    };

    loadHalf(P0, 0);
    loadHalf(P1, 1);

    f32x4 acc[16];

    #pragma unroll
    for (int s = 0; s < 16; ++s) {
        if ((s & 1) == 0) {                // new tile: acc init = bias
            #pragma unroll
            for (int nf = 0; nf < 16; ++nf)
                acc[nf] = *reinterpret_cast<const f32x4*>(&Bl[nf * 16 + q * 4]);
        }

        f32x4 (&Pc)[4][2] = (s & 1) ? P1 : P0;   // static after unroll

        #pragma unroll
        for (int k = 0; k < 4; ++k) {
            int ks = (s & 1) * 4 + k;
            short8 af = cvt8(Pc[k][0], Pc[k][1]);
            #pragma unroll
            for (int nf = 0; nf < 16; ++nf) {
                short8 bf = *reinterpret_cast<const short8*>(
                    wl + lq + ks * 16384 + nf * 256);
                acc[nf] = __builtin_amdgcn_mfma_f32_16x16x32_bf16(
                    bf, af, acc[nf], 0, 0, 0);   // swapped: out^T frag
            }
        }

        if (s < 14) loadHalf((s & 1) ? P1 : P0, s + 2);   // refill freed buffer

        if (s & 1) {                       // tile finished: store 16x256
            float* op = ow + (size_t)(s >> 1) * 16 * OUT_SZ;
            #pragma unroll
            for (int nf = 0; nf < 16; ++nf)
                *reinterpret_cast<f32x4*>(op + nf * 16) = acc[nf];
        }
    }
}

extern "C" void kernel_launch(void* const* d_in, const int* in_sizes, int n_in,
                              void* d_out, int out_size, void* d_ws, size_t ws_size,
                              hipStream_t stream) {
    const float* x    = (const float*)d_in[0];
    const int*   idx  = (const int*)  d_in[1];
    const float* U    = (const float*)d_in[2];
    const float* V    = (const float*)d_in[3];
    const float* bias = (const float*)d_in[4];
    float* out = (float*)d_out;
    unsigned short* wt = (unsigned short*)d_ws;   // 32 MB scratch
    (void)in_sizes; (void)n_in; (void)out_size; (void)ws_size;

    synth_w<<<dim3(512), dim3(256), 0, stream>>>(U, V, idx, wt);
    gemm_k <<<dim3(256), dim3(512), 0, stream>>>(x, idx, wt, bias, out);
}